// Round 3
// baseline (341.689 us; speedup 1.0000x reference)
//
#include <hip/hip_runtime.h>
#include <hip/hip_fp16.h>
#include <math.h>

#define BB 64
#define TT 512
#define DD 256
#define CC 20
#define SS 32          // segments
#define LL 16          // steps per segment
#define PROW 24        // padded f16 row stride (20 data + 4 pad -> 48B, 16B-aligned)
#define LN_EPS 1e-5f

// ws layout (bytes)
#define PROBS_OFF 0
#define PROBS_BYTES ((size_t)BB * TT * PROW * 2)              // 1,572,864
#define PBUF_OFF (PROBS_OFF + PROBS_BYTES)
#define PBUF_BYTES ((size_t)BB * SS * CC * PROW * 2)          // 1,966,080
#define SCALE_OFF (PBUF_OFF + PBUF_BYTES)
#define SCALE_BYTES ((size_t)BB * SS * 4)                     // 8,192
#define GOLD_OFF (SCALE_OFF + SCALE_BYTES)
#define GOLD_BYTES ((size_t)BB * 4)

__device__ __forceinline__ float dpp_sum16(float v) {
  v += __int_as_float(__builtin_amdgcn_update_dpp(0, __float_as_int(v), 0xB1, 0xF, 0xF, true));
  v += __int_as_float(__builtin_amdgcn_update_dpp(0, __float_as_int(v), 0x4E, 0xF, 0xF, true));
  v += __int_as_float(__builtin_amdgcn_update_dpp(0, __float_as_int(v), 0x141, 0xF, 0xF, true));
  v += __int_as_float(__builtin_amdgcn_update_dpp(0, __float_as_int(v), 0x140, 0xF, 0xF, true));
  return v;
}

__device__ __forceinline__ __half2 h2bc(float f) {
  return __builtin_bit_cast(__half2, f);
}

// ---- Kernel A: emb gather + LN + linear + softmax probs (f16) + gold score ----
// 16 lanes per token, 16 tokens per 256-thread block, grid 2048.
// NO dynamic register indexing anywhere (select trees instead) -> no scratch.
__global__ __launch_bounds__(256) void token_probs_kernel(
    const int* __restrict__ words, const float* __restrict__ emb,
    const float* __restrict__ ln_g, const float* __restrict__ ln_b,
    const float* __restrict__ W, const float* __restrict__ bias,
    const int* __restrict__ seq_len, const int* __restrict__ target,
    const float* __restrict__ trans, const float* __restrict__ startv,
    const float* __restrict__ endv,
    __half* __restrict__ probs, float* __restrict__ gold)
{
  __shared__ __align__(16) float4 sW4[64 * 21];
  __shared__ float sb[CC];
  int tid = threadIdx.x;
  for (int ei = tid; ei < 64 * CC; ei += 256) {
    int d4 = ei / CC, c = ei - d4 * CC;
    int base = 4 * d4 * CC + c;  // W is (D, C) row-major
    sW4[d4 * 21 + c] = make_float4(W[base], W[base + CC], W[base + 2 * CC], W[base + 3 * CC]);
  }
  if (tid < CC) sb[tid] = bias[tid];
  __syncthreads();

  int lane = tid & 63, wave = tid >> 6;
  int sub = lane >> 4, l = lane & 15;
  int token = blockIdx.x * 16 + wave * 4 + sub;

  int word = words[token];
  const float4* row = (const float4*)(emb + (size_t)word * DD);
  float4 x4[4], g4[4], b4[4];
  #pragma unroll
  for (int q = 0; q < 4; ++q) {
    x4[q] = row[l + 16 * q];
    g4[q] = ((const float4*)ln_g)[l + 16 * q];
    b4[q] = ((const float4*)ln_b)[l + 16 * q];
  }

  float s1 = 0.f, s2 = 0.f;
  #pragma unroll
  for (int q = 0; q < 4; ++q) {
    s1 += (x4[q].x + x4[q].y) + (x4[q].z + x4[q].w);
    s2 += (x4[q].x * x4[q].x + x4[q].y * x4[q].y) + (x4[q].z * x4[q].z + x4[q].w * x4[q].w);
  }
  s1 = dpp_sum16(s1);
  s2 = dpp_sum16(s2);
  float mu = s1 * (1.f / DD);
  float var = s2 * (1.f / DD) - mu * mu;
  float rr = rsqrtf(var + LN_EPS);

  float4 xn[4];
  #pragma unroll
  for (int q = 0; q < 4; ++q) {
    xn[q].x = (x4[q].x - mu) * rr * g4[q].x + b4[q].x;
    xn[q].y = (x4[q].y - mu) * rr * g4[q].y + b4[q].y;
    xn[q].z = (x4[q].z - mu) * rr * g4[q].z + b4[q].z;
    xn[q].w = (x4[q].w - mu) * rr * g4[q].w + b4[q].w;
  }

  float p[CC];
  #pragma unroll
  for (int c = 0; c < CC; ++c) p[c] = 0.f;
  #pragma unroll
  for (int q = 0; q < 4; ++q) {
    const float4* wrow = &sW4[(l + 16 * q) * 21];
    #pragma unroll
    for (int c = 0; c < CC; ++c) {
      float4 w = wrow[c];
      p[c] += (xn[q].x * w.x + xn[q].y * w.y) + (xn[q].z * w.z + xn[q].w * w.w);
    }
  }

  float feats[CC];
  #pragma unroll
  for (int c = 0; c < CC; ++c) feats[c] = dpp_sum16(p[c]) + sb[c];

  float m = feats[0];
  #pragma unroll
  for (int c = 1; c < CC; ++c) m = fmaxf(m, feats[c]);
  float ev[CC];
  float ssum = 0.f;
  #pragma unroll
  for (int c = 0; c < CC; ++c) { ev[c] = __expf(feats[c] - m); ssum += ev[c]; }
  float inv = 1.0f / ssum;
  float lsm = m + __logf(ssum);

  // store probs row: lane l<10 stores pair (2l, 2l+1). Constant-index select tree.
  float v0 = 0.f, v1 = 0.f;
  #pragma unroll
  for (int mm = 0; mm < 10; ++mm) {
    if (l == mm) { v0 = ev[2 * mm]; v1 = ev[2 * mm + 1]; }
  }
  __half2* pt2 = (__half2*)(probs + (size_t)token * PROW);
  if (l < 10) pt2[l] = __floats2half2_rn(v0 * inv, v1 * inv);

  // gold score contribution (one lane per token)
  int b = token >> 9, t = token & 511;
  int len = seq_len[b];
  if (l == 0 && t < len) {
    int tgt = target[token];
    float gsel = 0.f;
    #pragma unroll
    for (int c = 0; c < CC; ++c) if (tgt == c) gsel = feats[c];
    float g = gsel - lsm;
    if (t > 0) g += trans[target[token - 1] * CC + tgt];
    if (t == 0) g += startv[tgt];
    if (t == len - 1) g += endv[tgt];
    atomicAdd(&gold[b], g);
  }
}

// ---- Kernel A2: per-segment 20x20 product matrices, thread-per-column-chain ----
// chain (b,s,k): v <- diag(pr_t) E^T v for t in segment; start v = e_k.
// State = 10 __half2 VGPRs; E staged in LDS (broadcast f16 reads); pure v_pk_fma_f16
// chain, zero cross-lane ops. Block = 320 threads = 16 (b,s) groups.
__global__ __launch_bounds__(320) void segment_kernel(
    const __half* __restrict__ probs, const int* __restrict__ seq_len,
    const float* __restrict__ trans,
    __half* __restrict__ Pbuf, float* __restrict__ scaleBuf)
{
  __shared__ __align__(16) __half sE[CC * PROW];  // exp(trans), padded rows
  __shared__ float smass[16 * CC];
  int tid = threadIdx.x;
  for (int ei = tid; ei < CC * PROW; ei += 320) {
    int i = ei / PROW, j = ei - i * PROW;
    sE[ei] = (j < CC) ? __float2half(__expf(trans[i * CC + j])) : __half(0.f);
  }
  __syncthreads();

  int g_local = tid / CC, k = tid - g_local * CC;
  int g = blockIdx.x * 16 + g_local;     // g = b*SS + s
  int b = g >> 5, s = g & (SS - 1);
  int len = seq_len[b];

  __half2 v2[10];
  #pragma unroll
  for (int mm = 0; mm < 10; ++mm)
    v2[mm] = __halves2half2(k == 2 * mm ? __half(1.f) : __half(0.f),
                            k == 2 * mm + 1 ? __half(1.f) : __half(0.f));

  int t0 = s * LL + 1;
  int tend = min(s * LL + LL, len - 1);
  for (int t = t0; t <= tend; ++t) {
    const float4* prp = (const float4*)(probs + ((size_t)b * TT + t) * PROW);
    float4 PA = prp[0], PB = prp[1];
    float2 PC = ((const float2*)prp)[4];
    __half2 pr[10];
    pr[0] = h2bc(PA.x); pr[1] = h2bc(PA.y); pr[2] = h2bc(PA.z); pr[3] = h2bc(PA.w);
    pr[4] = h2bc(PB.x); pr[5] = h2bc(PB.y); pr[6] = h2bc(PB.z); pr[7] = h2bc(PB.w);
    pr[8] = h2bc(PC.x); pr[9] = h2bc(PC.y);

    __half2 out2[10];
    #pragma unroll
    for (int mm = 0; mm < 10; ++mm) out2[mm] = __floats2half2_rn(0.f, 0.f);

    #pragma unroll
    for (int i = 0; i < CC; ++i) {
      __half2 vi = (i & 1) ? __high2half2(v2[i >> 1]) : __low2half2(v2[i >> 1]);
      const float4* er = (const float4*)(sE + i * PROW);
      float4 E0 = er[0], E1 = er[1];
      float2 E2v = ((const float2*)er)[4];
      out2[0] = __hfma2(h2bc(E0.x), vi, out2[0]);
      out2[1] = __hfma2(h2bc(E0.y), vi, out2[1]);
      out2[2] = __hfma2(h2bc(E0.z), vi, out2[2]);
      out2[3] = __hfma2(h2bc(E0.w), vi, out2[3]);
      out2[4] = __hfma2(h2bc(E1.x), vi, out2[4]);
      out2[5] = __hfma2(h2bc(E1.y), vi, out2[5]);
      out2[6] = __hfma2(h2bc(E1.z), vi, out2[6]);
      out2[7] = __hfma2(h2bc(E1.w), vi, out2[7]);
      out2[8] = __hfma2(h2bc(E2v.x), vi, out2[8]);
      out2[9] = __hfma2(h2bc(E2v.y), vi, out2[9]);
    }
    #pragma unroll
    for (int mm = 0; mm < 10; ++mm) v2[mm] = __hmul2(out2[mm], pr[mm]);
  }

  // normalize segment matrix by max column mass (shared per group), log the scale
  float mass = 0.f;
  #pragma unroll
  for (int mm = 0; mm < 10; ++mm) {
    float2 f = __half22float2(v2[mm]);
    mass += f.x + f.y;
  }
  smass[g_local * CC + k] = mass;
  __syncthreads();
  float mx = 0.f;
  #pragma unroll
  for (int i = 0; i < CC; ++i) mx = fmaxf(mx, smass[g_local * CC + i]);
  float minv = 1.0f / mx;
  __half2 hs = __float2half2_rn(minv);
  __half2* col2 = (__half2*)(Pbuf + ((size_t)g * CC + k) * PROW);
  #pragma unroll
  for (int mm = 0; mm < 10; ++mm) col2[mm] = __hmul2(v2[mm], hs);
  if (k == 0) scaleBuf[g] = __logf(mx);
}

// ---- Kernel B: apply 32 segment matrices serially, replicated-alpha (no
// cross-lane in chain), then normalizer - gold -> atomic mean ----
__global__ __launch_bounds__(64) void combine_kernel(
    const __half* __restrict__ probs, const __half* __restrict__ Pbuf,
    const float* __restrict__ scaleBuf, const float* __restrict__ startv,
    const float* __restrict__ endv, const float* __restrict__ gold,
    float* __restrict__ out)
{
  int b = blockIdx.x;

  // p0 = pr_0 * exp(start), replicated in every lane
  const float4* prp = (const float4*)(probs + (size_t)b * TT * PROW);
  float4 PA = prp[0], PB = prp[1];
  float2 PC = ((const float2*)prp)[4];
  __half2 prh[10];
  prh[0] = h2bc(PA.x); prh[1] = h2bc(PA.y); prh[2] = h2bc(PA.z); prh[3] = h2bc(PA.w);
  prh[4] = h2bc(PB.x); prh[5] = h2bc(PB.y); prh[6] = h2bc(PB.z); prh[7] = h2bc(PB.w);
  prh[8] = h2bc(PC.x); prh[9] = h2bc(PC.y);

  float p0[CC];
  float mass0 = 0.f;
  #pragma unroll
  for (int mm = 0; mm < 10; ++mm) {
    float2 f = __half22float2(prh[mm]);
    p0[2 * mm]     = f.x * __expf(startv[2 * mm]);
    p0[2 * mm + 1] = f.y * __expf(startv[2 * mm + 1]);
    mass0 += p0[2 * mm] + p0[2 * mm + 1];
  }
  float Z = __logf(mass0);
  float inv0 = 1.0f / mass0;
  __half2 a2[10];
  #pragma unroll
  for (int mm = 0; mm < 10; ++mm)
    a2[mm] = __floats2half2_rn(p0[2 * mm] * inv0, p0[2 * mm + 1] * inv0);

  for (int s = 0; s < SS; ++s) {
    const __half* base = Pbuf + ((size_t)(b * SS + s) * CC) * PROW;
    __half2 out2[10];
    #pragma unroll
    for (int mm = 0; mm < 10; ++mm) out2[mm] = __floats2half2_rn(0.f, 0.f);
    #pragma unroll
    for (int i = 0; i < CC; ++i) {
      __half2 ai = (i & 1) ? __high2half2(a2[i >> 1]) : __low2half2(a2[i >> 1]);
      const float4* cp = (const float4*)(base + i * PROW);
      float4 c0 = cp[0], c1 = cp[1];
      float2 c2 = ((const float2*)cp)[4];
      out2[0] = __hfma2(h2bc(c0.x), ai, out2[0]);
      out2[1] = __hfma2(h2bc(c0.y), ai, out2[1]);
      out2[2] = __hfma2(h2bc(c0.z), ai, out2[2]);
      out2[3] = __hfma2(h2bc(c0.w), ai, out2[3]);
      out2[4] = __hfma2(h2bc(c1.x), ai, out2[4]);
      out2[5] = __hfma2(h2bc(c1.y), ai, out2[5]);
      out2[6] = __hfma2(h2bc(c1.z), ai, out2[6]);
      out2[7] = __hfma2(h2bc(c1.w), ai, out2[7]);
      out2[8] = __hfma2(h2bc(c2.x), ai, out2[8]);
      out2[9] = __hfma2(h2bc(c2.y), ai, out2[9]);
    }
    float mass = 0.f;
    #pragma unroll
    for (int mm = 0; mm < 10; ++mm) {
      float2 f = __half22float2(out2[mm]);
      mass += f.x + f.y;
    }
    Z += __logf(mass) + scaleBuf[b * SS + s];
    __half2 hs = __float2half2_rn(1.0f / mass);
    #pragma unroll
    for (int mm = 0; mm < 10; ++mm) a2[mm] = __hmul2(out2[mm], hs);
  }

  float sacc = 0.f;
  #pragma unroll
  for (int mm = 0; mm < 10; ++mm) {
    float2 f = __half22float2(a2[mm]);
    sacc += f.x * __expf(endv[2 * mm]) + f.y * __expf(endv[2 * mm + 1]);
  }
  float norm = Z + __logf(sacc);
  if (threadIdx.x == 0) atomicAdd(out, (norm - gold[b]) * (1.0f / BB));
}

extern "C" void kernel_launch(void* const* d_in, const int* in_sizes, int n_in,
                              void* d_out, int out_size, void* d_ws, size_t ws_size,
                              hipStream_t stream) {
  const int*   words   = (const int*)d_in[0];
  const int*   seq_len = (const int*)d_in[1];
  const int*   target  = (const int*)d_in[2];
  const float* emb     = (const float*)d_in[3];
  const float* ln_g    = (const float*)d_in[4];
  const float* ln_b    = (const float*)d_in[5];
  const float* W       = (const float*)d_in[6];
  const float* bias    = (const float*)d_in[7];
  const float* trans   = (const float*)d_in[8];
  const float* startv  = (const float*)d_in[9];
  const float* endv    = (const float*)d_in[10];

  char* ws = (char*)d_ws;
  __half* probs    = (__half*)(ws + PROBS_OFF);
  __half* Pbuf     = (__half*)(ws + PBUF_OFF);
  float*  scaleBuf = (float*)(ws + SCALE_OFF);
  float*  gold     = (float*)(ws + GOLD_OFF);
  float*  out      = (float*)d_out;

  hipMemsetAsync(out, 0, sizeof(float), stream);
  hipMemsetAsync(gold, 0, GOLD_BYTES, stream);

  token_probs_kernel<<<2048, 256, 0, stream>>>(words, emb, ln_g, ln_b, W, bias,
                                               seq_len, target, trans, startv,
                                               endv, probs, gold);
  segment_kernel<<<128, 320, 0, stream>>>(probs, seq_len, trans, Pbuf, scaleBuf);
  combine_kernel<<<BB, 64, 0, stream>>>(probs, Pbuf, scaleBuf, startv, endv,
                                        gold, out);
}